// Round 4
// baseline (530.283 us; speedup 1.0000x reference)
//
#include <hip/hip_runtime.h>

// H=256, B=512 graphs, N=200000 nodes, 3 steps.
#define HID 256
#define NG 512

__device__ __forceinline__ float sigmoidf_(float v) { return 1.f / (1.f + __expf(-v)); }

// ---------------------------------------------------------------------------
// Fused setup: blocks [0,2048) build Wcat/bcat, blocks [2048,2051) binary-search
// the per-graph start offsets.
__global__ __launch_bounds__(256) void setup_kernel(
    const float* __restrict__ W_ih, const float* __restrict__ W_hh,
    const float* __restrict__ b_ih, const float* __restrict__ b_hh,
    float* __restrict__ Wcat, float* __restrict__ bcat,
    const int* __restrict__ batch, int n, int* __restrict__ starts)
{
    int b = blockIdx.x;
    if (b < 2048) {
        int idx = b * 256 + threadIdx.x;
        int k = idx & 511;
        float v = W_ih[idx];
        if (k < 256) v += W_hh[(idx >> 9) * 256 + k];
        Wcat[idx] = v;
        if (idx < 1024) bcat[idx] = b_ih[idx] + b_hh[idx];
    } else {
        int g = (b - 2048) * 256 + threadIdx.x;
        if (g > NG) return;
        if (g == NG) { starts[NG] = n; return; }
        int lo = 0, hi = n;
        while (lo < hi) {
            int mid = (lo + hi) >> 1;
            if (batch[mid] < g) lo = mid + 1; else hi = mid;
        }
        starts[g] = lo;
    }
}

// ---------------------------------------------------------------------------
// Fused LSTM cell + attention + partial readout. FOUR blocks per graph
// (blockIdx = g*4 + part); each block is 4 waves, wave w of part p owns
// 8-row chunks c ≡ p*4+w (mod 16). VGPR capped at 128 (launch_bounds 4
// waves/EU) -> 16 waves/CU, 4 blocks/CU: q fragments come from LDS
// (broadcast ds_read_b128) and the racc rescale is deferred to new-max
// events (wave-uniform branch, bitwise-equivalent). Per-part online-softmax
// partials (r[256], m, l) written to pr; merge_kernel normalizes.
__global__ __launch_bounds__(256, 4) void attn_kernel(
    const float* __restrict__ x, const int* __restrict__ starts,
    const float* __restrict__ gates_p,      // [2][512][1024] split-K partials
    const float* __restrict__ bcat,
    const float* __restrict__ cs_r, float* __restrict__ cs_w,
    float* __restrict__ qs, float* __restrict__ pr, int step0)
{
    __shared__ __align__(16) float ql[HID];
    __shared__ __align__(16) float red[4][HID];
    __shared__ float mw[4], lw[4];

    const int g = blockIdx.x >> 2, part = blockIdx.x & 3;
    const int tid = threadIdx.x;

    // ---- LSTM cell for hidden unit `tid` (gate order i,f,g,o).
    // Redundant across the 4 parts; only part 0 writes cs/qs. cs is
    // ping-ponged across steps so parts never race on it.
    {
        float ig = bcat[tid], fg = bcat[256 + tid], gg = bcat[512 + tid], og = bcat[768 + tid];
        float cp = 0.f;
        if (!step0) {
            const float* a = gates_p + (size_t)g * 1024;
            const size_t ss = (size_t)512 * 1024;
            #pragma unroll
            for (int z = 0; z < 2; ++z) {
                const float* az = a + z * ss;
                ig += az[tid]; fg += az[256 + tid]; gg += az[512 + tid]; og += az[768 + tid];
            }
            cp = cs_r[g * HID + tid];
        }
        float cn = sigmoidf_(fg) * cp + sigmoidf_(ig) * tanhf(gg);
        float h  = sigmoidf_(og) * tanhf(cn);
        if (part == 0) {
            cs_w[g * HID + tid] = cn;
            qs[(size_t)g * 512 + tid] = h;      // q_star[:, :256] = hs
        }
        ql[tid] = h;
    }

    const int s0 = starts[g];
    const int nn = starts[g + 1] - s0;
    if (nn <= 0) return;                        // merge_kernel writes zeros
    __syncthreads();

    const int w = tid >> 6, lane = tid & 63;
    const int j = lane >> 3;        // row within 8-row chunk
    const int s = lane & 7;         // 16B column-group within row

    const int nch = (nn + 7) >> 3;              // 8-row chunks
    const int last = s0 + nn - 1;
    const float NEG = -3.402823466e38f;

    float m_run = NEG, l_run = 0.f;
    float4 racc[8] = {};
    float4 xc[8], xn[8];

    int c = part * 4 + w;                       // chunks stride 16
    if (c < nch) {
        int node = s0 + c * 8 + j; if (node > last) node = last;
        const float* bp = x + (size_t)node * HID + s * 4;
        #pragma unroll
        for (int k = 0; k < 8; ++k) xc[k] = *(const float4*)(bp + k * 32);
    }
    for (; c < nch; c += 16) {
        if (c + 16 < nch) {
            int node = s0 + (c + 16) * 8 + j; if (node > last) node = last;
            const float* bp = x + (size_t)node * HID + s * 4;
            #pragma unroll
            for (int k = 0; k < 8; ++k) xn[k] = *(const float4*)(bp + k * 32);
        }
        const bool valid = (c * 8 + j) < nn;    // j=0 always valid for c<nch

        float e = 0.f;
        #pragma unroll
        for (int k = 0; k < 8; ++k) {
            float4 q = *(const float4*)&ql[k * 32 + s * 4];   // LDS broadcast
            e += xc[k].x * q.x + xc[k].y * q.y + xc[k].z * q.z + xc[k].w * q.w;
        }
        e += __shfl_xor(e, 1); e += __shfl_xor(e, 2); e += __shfl_xor(e, 4);
        e = valid ? e : NEG;

        float mc = fmaxf(e, __shfl_xor(e, 8));
        mc = fmaxf(mc, __shfl_xor(mc, 16));
        mc = fmaxf(mc, __shfl_xor(mc, 32));     // wave-uniform chunk max
        if (mc > m_run) {                       // wave-uniform new-max event
            float alpha = __expf(m_run - mc);   // first event: expf(-3.4e38)=0
            l_run *= alpha;
            #pragma unroll
            for (int k = 0; k < 8; ++k) {
                racc[k].x *= alpha; racc[k].y *= alpha;
                racc[k].z *= alpha; racc[k].w *= alpha;
            }
            m_run = mc;
        }
        float p = valid ? __expf(e - m_run) : 0.f;
        float ps = p;
        ps += __shfl_xor(ps, 8); ps += __shfl_xor(ps, 16); ps += __shfl_xor(ps, 32);
        l_run += ps;
        #pragma unroll
        for (int k = 0; k < 8; ++k) {
            racc[k].x += p * xc[k].x;
            racc[k].y += p * xc[k].y;
            racc[k].z += p * xc[k].z;
            racc[k].w += p * xc[k].w;
        }
        #pragma unroll
        for (int k = 0; k < 8; ++k) xc[k] = xn[k];
    }

    // fold racc across the 8 row-slots (lane bits 3..5)
    #pragma unroll
    for (int k = 0; k < 8; ++k) {
        racc[k].x += __shfl_xor(racc[k].x, 8);
        racc[k].y += __shfl_xor(racc[k].y, 8);
        racc[k].z += __shfl_xor(racc[k].z, 8);
        racc[k].w += __shfl_xor(racc[k].w, 8);
        racc[k].x += __shfl_xor(racc[k].x, 16);
        racc[k].y += __shfl_xor(racc[k].y, 16);
        racc[k].z += __shfl_xor(racc[k].z, 16);
        racc[k].w += __shfl_xor(racc[k].w, 16);
        racc[k].x += __shfl_xor(racc[k].x, 32);
        racc[k].y += __shfl_xor(racc[k].y, 32);
        racc[k].z += __shfl_xor(racc[k].z, 32);
        racc[k].w += __shfl_xor(racc[k].w, 32);
    }
    if (j == 0) {
        #pragma unroll
        for (int k = 0; k < 8; ++k) *(float4*)&red[w][k * 32 + s * 4] = racc[k];
        if (s == 0) { mw[w] = m_run; lw[w] = l_run; }
    }
    __syncthreads();

    // merge this part's 4 wave-states; write UNNORMALIZED partial (R, M, L)
    float M = fmaxf(fmaxf(mw[0], mw[1]), fmaxf(mw[2], mw[3]));
    float f0 = __expf(mw[0] - M), f1 = __expf(mw[1] - M);
    float f2 = __expf(mw[2] - M), f3 = __expf(mw[3] - M);
    float L = lw[0] * f0 + lw[1] * f1 + lw[2] * f2 + lw[3] * f3;
    float R = red[0][tid] * f0 + red[1][tid] * f1 + red[2][tid] * f2 + red[3][tid] * f3;
    float* pb = pr + (size_t)(((size_t)g << 2) + part) * 260;
    pb[tid] = R;
    if (tid == 0) { pb[256] = M; pb[257] = L; }
}

// ---------------------------------------------------------------------------
// Merge the 4 per-part partials of each graph into q_star[:, 256:512].
__global__ __launch_bounds__(256) void merge_kernel(
    const float* __restrict__ pr, const int* __restrict__ starts,
    float* __restrict__ qs)
{
    const int g = blockIdx.x, tid = threadIdx.x;
    const int nn = starts[g + 1] - starts[g];
    if (nn <= 0) { qs[(size_t)g * 512 + HID + tid] = 0.f; return; }
    const float* pb = pr + (size_t)g * 4 * 260;
    float m0 = pb[256], m1 = pb[260 + 256], m2 = pb[2 * 260 + 256], m3 = pb[3 * 260 + 256];
    float M = fmaxf(fmaxf(m0, m1), fmaxf(m2, m3));   // finite: part 0 owns chunk 0
    float f0 = __expf(m0 - M), f1 = __expf(m1 - M);
    float f2 = __expf(m2 - M), f3 = __expf(m3 - M);
    float L = pb[257] * f0 + pb[260 + 257] * f1 + pb[2 * 260 + 257] * f2 + pb[3 * 260 + 257] * f3;
    float R = pb[tid] * f0 + pb[260 + tid] * f1 + pb[2 * 260 + tid] * f2 + pb[3 * 260 + tid] * f3;
    qs[(size_t)g * 512 + HID + tid] = R / L;
}

// ---------------------------------------------------------------------------
// Cp[z][M x N] = A[M x K-slice] * B[N x K-slice]^T ; 64x64 tile, 4x4 micro,
// b128 LDS reads both operands, global prefetch. grid (N/64, M/64, S).
__global__ __launch_bounds__(256) void gemm_splitk(
    const float* __restrict__ A, int lda,
    const float* __restrict__ B, int ldb,
    float* __restrict__ Cp, int ldc, int KS, size_t slice_stride)
{
    __shared__ float As[16][76];
    __shared__ float Bs[16][76];
    const int tid = threadIdx.x;
    const int tx = tid & 15, ty = tid >> 4;
    const int m0 = blockIdx.y * 64, n0 = blockIdx.x * 64;
    const int kb = blockIdx.z * KS;
    const int r = tid >> 2, kc = (tid & 3) << 2;
    float acc[4][4] = {};

    const float* Ap = &A[(size_t)(m0 + r) * lda + kb + kc];
    const float* Bp = &B[(size_t)(n0 + r) * ldb + kb + kc];
    float4 av = *(const float4*)Ap;
    float4 bv = *(const float4*)Bp;

    for (int k0 = 0; k0 < KS; k0 += 16) {
        As[kc + 0][r] = av.x; As[kc + 1][r] = av.y; As[kc + 2][r] = av.z; As[kc + 3][r] = av.w;
        Bs[kc + 0][r] = bv.x; Bs[kc + 1][r] = bv.y; Bs[kc + 2][r] = bv.z; Bs[kc + 3][r] = bv.w;
        __syncthreads();
        if (k0 + 16 < KS) {
            av = *(const float4*)(Ap + k0 + 16);
            bv = *(const float4*)(Bp + k0 + 16);
        }
        #pragma unroll
        for (int kk = 0; kk < 16; ++kk) {
            float4 a = *(const float4*)&As[kk][ty << 2];
            float4 b = *(const float4*)&Bs[kk][tx << 2];
            acc[0][0] += a.x * b.x; acc[0][1] += a.x * b.y; acc[0][2] += a.x * b.z; acc[0][3] += a.x * b.w;
            acc[1][0] += a.y * b.x; acc[1][1] += a.y * b.y; acc[1][2] += a.y * b.z; acc[1][3] += a.y * b.w;
            acc[2][0] += a.z * b.x; acc[2][1] += a.z * b.y; acc[2][2] += a.z * b.z; acc[2][3] += a.z * b.w;
            acc[3][0] += a.w * b.x; acc[3][1] += a.w * b.y; acc[3][2] += a.w * b.z; acc[3][3] += a.w * b.w;
        }
        __syncthreads();
    }
    float* out = Cp + blockIdx.z * slice_stride;
    #pragma unroll
    for (int i = 0; i < 4; ++i) {
        float4 o = make_float4(acc[i][0], acc[i][1], acc[i][2], acc[i][3]);
        *(float4*)&out[(size_t)(m0 + ty * 4 + i) * ldc + n0 + (tx << 2)] = o;
    }
}

// ---------------------------------------------------------------------------
__global__ __launch_bounds__(256) void finalize_out(
    const float* __restrict__ op, const float* __restrict__ b_out,
    float* __restrict__ out)
{
    int i = blockIdx.x * 256 + threadIdx.x;
    if (i < 512 * 256) {
        float v = op[i] + op[131072 + i] + op[262144 + i] + op[393216 + i] + b_out[i & 255];
        out[i] = v;
    }
}

// ---------------------------------------------------------------------------
extern "C" void kernel_launch(void* const* d_in, const int* in_sizes, int n_in,
                              void* d_out, int out_size, void* d_ws, size_t ws_size,
                              hipStream_t stream)
{
    const float* x     = (const float*)d_in[0];
    const int*   batch = (const int*)d_in[1];
    const float* W_ih  = (const float*)d_in[2];
    const float* W_hh  = (const float*)d_in[3];
    const float* b_ih  = (const float*)d_in[4];
    const float* b_hh  = (const float*)d_in[5];
    const float* W_out = (const float*)d_in[6];
    const float* b_out = (const float*)d_in[7];
    float* out = (float*)d_out;
    const int n = in_sizes[1];
    (void)n_in; (void)out_size; (void)ws_size;

    char* ws = (char*)d_ws;
    float* qs      = (float*)(ws);                  // [512][512]      1 MB
    float* csA     = (float*)(ws + 0x100000);       // [512][256]      512 KB
    float* csB     = (float*)(ws + 0x180000);       // [512][256]      512 KB
    float* gates_p = (float*)(ws + 0x200000);       // [2][512][1024]  4 MB
    float* Wcat    = (float*)(ws + 0x600000);       // [1024][512]     2 MB
    float* bcat    = (float*)(ws + 0x800000);       // [1024]
    int*   starts  = (int*)  (ws + 0x801000);       // [513]
    float* pr      = (float*)(ws + 0x810000);       // [512*4][260]    2.13 MB
    float* out_p   = (float*)(ws + 0xA20000);       // [4][512][256]   2 MB (ends 0xC20000 ≈ 12.1 MiB)

    setup_kernel<<<2051, 256, 0, stream>>>(W_ih, W_hh, b_ih, b_hh, Wcat, bcat,
                                           batch, n, starts);

    for (int step = 0; step < 3; ++step) {
        if (step > 0) {
            gemm_splitk<<<dim3(16, 8, 2), 256, 0, stream>>>(
                qs, 512, Wcat, 512, gates_p, 1024, 256, (size_t)512 * 1024);
        }
        const float* cs_r = (step == 2) ? csB : csA;   // step1 reads csA
        float*       cs_w = (step == 1) ? csB : csA;   // step0->csA, step1->csB, step2->csA
        attn_kernel<<<NG * 4, 256, 0, stream>>>(
            x, starts, gates_p, bcat, cs_r, cs_w, qs, pr, step == 0);
        merge_kernel<<<NG, 256, 0, stream>>>(pr, starts, qs);
    }
    gemm_splitk<<<dim3(4, 8, 4), 256, 0, stream>>>(
        qs, 512, W_out, 512, out_p, 256, 128, (size_t)512 * 256);
    finalize_out<<<512, 256, 0, stream>>>(out_p, b_out, out);
}

// Round 5
// 514.815 us; speedup vs baseline: 1.0300x; 1.0300x over previous
//
#include <hip/hip_runtime.h>

// H=256, B=512 graphs, N=200000 nodes, 3 steps.
#define HID 256
#define NG 512

__device__ __forceinline__ float sigmoidf_(float v) { return 1.f / (1.f + __expf(-v)); }

// ---------------------------------------------------------------------------
// Fused setup: blocks [0,2048) build Wcat/bcat, blocks [2048,2051) binary-search
// the per-graph start offsets.
__global__ __launch_bounds__(256) void setup_kernel(
    const float* __restrict__ W_ih, const float* __restrict__ W_hh,
    const float* __restrict__ b_ih, const float* __restrict__ b_hh,
    float* __restrict__ Wcat, float* __restrict__ bcat,
    const int* __restrict__ batch, int n, int* __restrict__ starts)
{
    int b = blockIdx.x;
    if (b < 2048) {
        int idx = b * 256 + threadIdx.x;
        int k = idx & 511;
        float v = W_ih[idx];
        if (k < 256) v += W_hh[(idx >> 9) * 256 + k];
        Wcat[idx] = v;
        if (idx < 1024) bcat[idx] = b_ih[idx] + b_hh[idx];
    } else {
        int g = (b - 2048) * 256 + threadIdx.x;
        if (g > NG) return;
        if (g == NG) { starts[NG] = n; return; }
        int lo = 0, hi = n;
        while (lo < hi) {
            int mid = (lo + hi) >> 1;
            if (batch[mid] < g) lo = mid + 1; else hi = mid;
        }
        starts[g] = lo;
    }
}

// ---------------------------------------------------------------------------
// E-kernel: fused LSTM cell (once per graph) + attention logits e = x.q.
// One block per graph, 4 waves; wave w owns 8-row chunks c ≡ w (mod 4).
// Hot loop: 8 coalesced float4 loads + 32 FMA + 3 shfl + one 4B store.
// No softmax state, no exp, no rescale — near-pure stream.
// NO launch_bounds VGPR cap (R4 showed the cap forces array spill: VGPR=64,
// WRITE_SIZE 72MB vs 3.6MB logical).
__global__ __launch_bounds__(256) void e_kernel(
    const float* __restrict__ x, const int* __restrict__ starts,
    const float* __restrict__ gates_p,      // [2][512][1024] split-K partials
    const float* __restrict__ bcat, float* __restrict__ cs,
    float* __restrict__ qs, float* __restrict__ e, int step0)
{
    __shared__ __align__(16) float ql[HID];

    const int g = blockIdx.x;
    const int tid = threadIdx.x;

    // ---- LSTM cell for hidden unit `tid` (gate order i,f,g,o)
    {
        float ig = bcat[tid], fg = bcat[256 + tid], gg = bcat[512 + tid], og = bcat[768 + tid];
        float cp = 0.f;
        if (!step0) {
            const float* a0 = gates_p + (size_t)g * 1024;
            const float* a1 = a0 + (size_t)512 * 1024;
            ig += a0[tid]       + a1[tid];
            fg += a0[256 + tid] + a1[256 + tid];
            gg += a0[512 + tid] + a1[512 + tid];
            og += a0[768 + tid] + a1[768 + tid];
            cp = cs[g * HID + tid];
        }
        float cn = sigmoidf_(fg) * cp + sigmoidf_(ig) * tanhf(gg);
        float h  = sigmoidf_(og) * tanhf(cn);
        cs[g * HID + tid] = cn;
        qs[(size_t)g * 512 + tid] = h;      // q_star[:, :256] = hs
        ql[tid] = h;
    }

    const int s0 = starts[g];
    const int nn = starts[g + 1] - s0;
    if (nn <= 0) return;
    __syncthreads();

    const int w = tid >> 6, lane = tid & 63;
    const int j = lane >> 3;        // row within 8-row chunk
    const int s = lane & 7;         // 16B column-group within row

    float4 qf[8];
    #pragma unroll
    for (int k = 0; k < 8; ++k) qf[k] = *(const float4*)&ql[k * 32 + s * 4];

    const int nch = (nn + 7) >> 3;
    const int last = s0 + nn - 1;

    float4 xc[8], xn[8];
    int c = w;
    if (c < nch) {
        int node = s0 + c * 8 + j; if (node > last) node = last;
        const float* bp = x + (size_t)node * HID + s * 4;
        #pragma unroll
        for (int k = 0; k < 8; ++k) xc[k] = *(const float4*)(bp + k * 32);
    }
    for (; c < nch; c += 4) {
        if (c + 4 < nch) {
            int node = s0 + (c + 4) * 8 + j; if (node > last) node = last;
            const float* bp = x + (size_t)node * HID + s * 4;
            #pragma unroll
            for (int k = 0; k < 8; ++k) xn[k] = *(const float4*)(bp + k * 32);
        }
        float ev = 0.f;
        #pragma unroll
        for (int k = 0; k < 8; ++k)
            ev += xc[k].x * qf[k].x + xc[k].y * qf[k].y + xc[k].z * qf[k].z + xc[k].w * qf[k].w;
        ev += __shfl_xor(ev, 1); ev += __shfl_xor(ev, 2); ev += __shfl_xor(ev, 4);
        if (s == 0 && (c * 8 + j) < nn) e[s0 + c * 8 + j] = ev;
        #pragma unroll
        for (int k = 0; k < 8; ++k) xc[k] = xn[k];
    }
}

// ---------------------------------------------------------------------------
// S-kernel: exact segment softmax. One block per graph over e[s0:s0+nn]
// (~390 elems, L1/L2-hot): a[i] = exp(e[i]-max)/sum.
__global__ __launch_bounds__(256) void s_kernel(
    const float* __restrict__ e, const int* __restrict__ starts,
    float* __restrict__ a)
{
    __shared__ float sm[4], sl[4];
    const int g = blockIdx.x, tid = threadIdx.x;
    const int s0 = starts[g];
    const int nn = starts[g + 1] - s0;
    if (nn <= 0) return;
    const int w = tid >> 6, lane = tid & 63;

    float m = -3.402823466e38f;
    for (int i = tid; i < nn; i += 256) m = fmaxf(m, e[s0 + i]);
    m = fmaxf(m, __shfl_xor(m, 1));  m = fmaxf(m, __shfl_xor(m, 2));
    m = fmaxf(m, __shfl_xor(m, 4));  m = fmaxf(m, __shfl_xor(m, 8));
    m = fmaxf(m, __shfl_xor(m, 16)); m = fmaxf(m, __shfl_xor(m, 32));
    if (lane == 0) sm[w] = m;
    __syncthreads();
    const float M = fmaxf(fmaxf(sm[0], sm[1]), fmaxf(sm[2], sm[3]));

    float l = 0.f;
    for (int i = tid; i < nn; i += 256) l += __expf(e[s0 + i] - M);
    l += __shfl_xor(l, 1);  l += __shfl_xor(l, 2);  l += __shfl_xor(l, 4);
    l += __shfl_xor(l, 8);  l += __shfl_xor(l, 16); l += __shfl_xor(l, 32);
    if (lane == 0) sl[w] = l;
    __syncthreads();
    const float L = sl[0] + sl[1] + sl[2] + sl[3];

    const float inv = 1.f / L;
    for (int i = tid; i < nn; i += 256) a[s0 + i] = __expf(e[s0 + i] - M) * inv;
}

// ---------------------------------------------------------------------------
// R-kernel: weighted readout r = sum_i a_i * x_i. One block per graph,
// 4 waves, chunks c ≡ w (mod 4). Hot loop: 8 float4 loads + 1 scalar a-load
// + 32 independent FMAs. ZERO shfl/exp in the loop; epilogue is a plain sum.
__global__ __launch_bounds__(256) void r_kernel(
    const float* __restrict__ x, const int* __restrict__ starts,
    const float* __restrict__ a, float* __restrict__ qs)
{
    __shared__ __align__(16) float red[4][HID];
    const int g = blockIdx.x, tid = threadIdx.x;
    const int s0 = starts[g];
    const int nn = starts[g + 1] - s0;
    if (nn <= 0) { qs[(size_t)g * 512 + HID + tid] = 0.f; return; }

    const int w = tid >> 6, lane = tid & 63;
    const int j = lane >> 3;
    const int s = lane & 7;
    const int nch = (nn + 7) >> 3;
    const int last = s0 + nn - 1;

    float4 racc[8] = {};
    float4 xc[8], xn[8];
    float ac = 0.f, an = 0.f;

    int c = w;
    if (c < nch) {
        int node = s0 + c * 8 + j; if (node > last) node = last;
        const float* bp = x + (size_t)node * HID + s * 4;
        #pragma unroll
        for (int k = 0; k < 8; ++k) xc[k] = *(const float4*)(bp + k * 32);
        ac = a[node];
    }
    for (; c < nch; c += 4) {
        if (c + 4 < nch) {
            int node = s0 + (c + 4) * 8 + j; if (node > last) node = last;
            const float* bp = x + (size_t)node * HID + s * 4;
            #pragma unroll
            for (int k = 0; k < 8; ++k) xn[k] = *(const float4*)(bp + k * 32);
            an = a[node];
        }
        const float p = ((c * 8 + j) < nn) ? ac : 0.f;
        #pragma unroll
        for (int k = 0; k < 8; ++k) {
            racc[k].x += p * xc[k].x;
            racc[k].y += p * xc[k].y;
            racc[k].z += p * xc[k].z;
            racc[k].w += p * xc[k].w;
        }
        #pragma unroll
        for (int k = 0; k < 8; ++k) xc[k] = xn[k];
        ac = an;
    }

    // fold racc across the 8 row-slots (lane bits 3..5)
    #pragma unroll
    for (int k = 0; k < 8; ++k) {
        racc[k].x += __shfl_xor(racc[k].x, 8);
        racc[k].y += __shfl_xor(racc[k].y, 8);
        racc[k].z += __shfl_xor(racc[k].z, 8);
        racc[k].w += __shfl_xor(racc[k].w, 8);
        racc[k].x += __shfl_xor(racc[k].x, 16);
        racc[k].y += __shfl_xor(racc[k].y, 16);
        racc[k].z += __shfl_xor(racc[k].z, 16);
        racc[k].w += __shfl_xor(racc[k].w, 16);
        racc[k].x += __shfl_xor(racc[k].x, 32);
        racc[k].y += __shfl_xor(racc[k].y, 32);
        racc[k].z += __shfl_xor(racc[k].z, 32);
        racc[k].w += __shfl_xor(racc[k].w, 32);
    }
    if (j == 0) {
        #pragma unroll
        for (int k = 0; k < 8; ++k) *(float4*)&red[w][k * 32 + s * 4] = racc[k];
    }
    __syncthreads();
    qs[(size_t)g * 512 + HID + tid] =
        red[0][tid] + red[1][tid] + red[2][tid] + red[3][tid];
}

// ---------------------------------------------------------------------------
// Cp[z][M x N] = A[M x K-slice] * B[N x K-slice]^T ; 64x64 tile, 4x4 micro,
// b128 LDS reads both operands, global prefetch. grid (N/64, M/64, S).
__global__ __launch_bounds__(256) void gemm_splitk(
    const float* __restrict__ A, int lda,
    const float* __restrict__ B, int ldb,
    float* __restrict__ Cp, int ldc, int KS, size_t slice_stride)
{
    __shared__ float As[16][76];
    __shared__ float Bs[16][76];
    const int tid = threadIdx.x;
    const int tx = tid & 15, ty = tid >> 4;
    const int m0 = blockIdx.y * 64, n0 = blockIdx.x * 64;
    const int kb = blockIdx.z * KS;
    const int r = tid >> 2, kc = (tid & 3) << 2;
    float acc[4][4] = {};

    const float* Ap = &A[(size_t)(m0 + r) * lda + kb + kc];
    const float* Bp = &B[(size_t)(n0 + r) * ldb + kb + kc];
    float4 av = *(const float4*)Ap;
    float4 bv = *(const float4*)Bp;

    for (int k0 = 0; k0 < KS; k0 += 16) {
        As[kc + 0][r] = av.x; As[kc + 1][r] = av.y; As[kc + 2][r] = av.z; As[kc + 3][r] = av.w;
        Bs[kc + 0][r] = bv.x; Bs[kc + 1][r] = bv.y; Bs[kc + 2][r] = bv.z; Bs[kc + 3][r] = bv.w;
        __syncthreads();
        if (k0 + 16 < KS) {
            av = *(const float4*)(Ap + k0 + 16);
            bv = *(const float4*)(Bp + k0 + 16);
        }
        #pragma unroll
        for (int kk = 0; kk < 16; ++kk) {
            float4 a = *(const float4*)&As[kk][ty << 2];
            float4 b = *(const float4*)&Bs[kk][tx << 2];
            acc[0][0] += a.x * b.x; acc[0][1] += a.x * b.y; acc[0][2] += a.x * b.z; acc[0][3] += a.x * b.w;
            acc[1][0] += a.y * b.x; acc[1][1] += a.y * b.y; acc[1][2] += a.y * b.z; acc[1][3] += a.y * b.w;
            acc[2][0] += a.z * b.x; acc[2][1] += a.z * b.y; acc[2][2] += a.z * b.z; acc[2][3] += a.z * b.w;
            acc[3][0] += a.w * b.x; acc[3][1] += a.w * b.y; acc[3][2] += a.w * b.z; acc[3][3] += a.w * b.w;
        }
        __syncthreads();
    }
    float* out = Cp + blockIdx.z * slice_stride;
    #pragma unroll
    for (int i = 0; i < 4; ++i) {
        float4 o = make_float4(acc[i][0], acc[i][1], acc[i][2], acc[i][3]);
        *(float4*)&out[(size_t)(m0 + ty * 4 + i) * ldc + n0 + (tx << 2)] = o;
    }
}

// ---------------------------------------------------------------------------
__global__ __launch_bounds__(256) void finalize_out(
    const float* __restrict__ op, const float* __restrict__ b_out,
    float* __restrict__ out)
{
    int i = blockIdx.x * 256 + threadIdx.x;
    if (i < 512 * 256) {
        float v = op[i] + op[131072 + i] + op[262144 + i] + op[393216 + i] + b_out[i & 255];
        out[i] = v;
    }
}

// ---------------------------------------------------------------------------
extern "C" void kernel_launch(void* const* d_in, const int* in_sizes, int n_in,
                              void* d_out, int out_size, void* d_ws, size_t ws_size,
                              hipStream_t stream)
{
    const float* x     = (const float*)d_in[0];
    const int*   batch = (const int*)d_in[1];
    const float* W_ih  = (const float*)d_in[2];
    const float* W_hh  = (const float*)d_in[3];
    const float* b_ih  = (const float*)d_in[4];
    const float* b_hh  = (const float*)d_in[5];
    const float* W_out = (const float*)d_in[6];
    const float* b_out = (const float*)d_in[7];
    float* out = (float*)d_out;
    const int n = in_sizes[1];
    (void)n_in; (void)out_size; (void)ws_size;

    char* ws = (char*)d_ws;
    float* qs      = (float*)(ws);                  // [512][512]      1 MB
    float* cs      = (float*)(ws + 0x100000);       // [512][256]      512 KB
    float* gates_p = (float*)(ws + 0x180000);       // [2][512][1024]  4 MB
    float* Wcat    = (float*)(ws + 0x580000);       // [1024][512]     2 MB
    float* bcat    = (float*)(ws + 0x780000);       // [1024]
    int*   starts  = (int*)  (ws + 0x781000);       // [513]
    float* e_buf   = (float*)(ws + 0x790000);       // [200000]        800 KB
    float* a_buf   = (float*)(ws + 0x860000);       // [200000]        800 KB
    float* out_p   = (float*)(ws + 0x930000);       // [4][512][256]   2 MB (ends 0xB30000 ≈ 11.2 MiB)

    setup_kernel<<<2051, 256, 0, stream>>>(W_ih, W_hh, b_ih, b_hh, Wcat, bcat,
                                           batch, n, starts);

    for (int step = 0; step < 3; ++step) {
        if (step > 0) {
            gemm_splitk<<<dim3(16, 8, 2), 256, 0, stream>>>(
                qs, 512, Wcat, 512, gates_p, 1024, 256, (size_t)512 * 1024);
        }
        e_kernel<<<NG, 256, 0, stream>>>(x, starts, gates_p, bcat, cs, qs,
                                         e_buf, step == 0);
        s_kernel<<<NG, 256, 0, stream>>>(e_buf, starts, a_buf);
        r_kernel<<<NG, 256, 0, stream>>>(x, starts, a_buf, qs);
    }
    gemm_splitk<<<dim3(4, 8, 4), 256, 0, stream>>>(
        qs, 512, W_out, 512, out_p, 256, 128, (size_t)512 * 256);
    finalize_out<<<512, 256, 0, stream>>>(out_p, b_out, out);
}

// Round 6
// 430.429 us; speedup vs baseline: 1.2320x; 1.1961x over previous
//
#include <hip/hip_runtime.h>

// H=256, B=512 graphs, N=200000 nodes, 3 steps.
#define HID 256
#define NG 512

__device__ __forceinline__ float sigmoidf_(float v) { return 1.f / (1.f + __expf(-v)); }

// ---------------------------------------------------------------------------
// Fused setup: blocks [0,2048) build Wcat/bcat, blocks [2048,2051) binary-search
// the per-graph start offsets.
__global__ __launch_bounds__(256) void setup_kernel(
    const float* __restrict__ W_ih, const float* __restrict__ W_hh,
    const float* __restrict__ b_ih, const float* __restrict__ b_hh,
    float* __restrict__ Wcat, float* __restrict__ bcat,
    const int* __restrict__ batch, int n, int* __restrict__ starts)
{
    int b = blockIdx.x;
    if (b < 2048) {
        int idx = b * 256 + threadIdx.x;
        int k = idx & 511;
        float v = W_ih[idx];
        if (k < 256) v += W_hh[(idx >> 9) * 256 + k];
        Wcat[idx] = v;
        if (idx < 1024) bcat[idx] = b_ih[idx] + b_hh[idx];
    } else {
        int g = (b - 2048) * 256 + threadIdx.x;
        if (g > NG) return;
        if (g == NG) { starts[NG] = n; return; }
        int lo = 0, hi = n;
        while (lo < hi) {
            int mid = (lo + hi) >> 1;
            if (batch[mid] < g) lo = mid + 1; else hi = mid;
        }
        starts[g] = lo;
    }
}

// ---------------------------------------------------------------------------
// Fused LSTM cell + attention + partial readout. FOUR blocks per graph
// (blockIdx = g*4 + part); each block is 4 waves, wave w of part p owns
// 8-row chunks c ≡ p*4+w (mod 16). NO VGPR cap: R4 showed __launch_bounds__
// (256,4) forces the compiler to 64 VGPRs and spills xc/xn/racc to scratch
// (WRITE_SIZE 70MB vs 3.6MB logical). Natural allocation ~110 VGPR -> 4
// waves/SIMD, 16 waves/CU: this is the clean 2x-occupancy A/B vs the 8
// waves/CU all previous clean variants ran at. q fragments come from LDS
// (broadcast ds_read_b128); racc rescale deferred to new-max events
// (wave-uniform branch). Per-part partials (r[256], m, l) -> pr; merged later.
__global__ __launch_bounds__(256) void attn_kernel(
    const float* __restrict__ x, const int* __restrict__ starts,
    const float* __restrict__ gates_p,      // [2][512][1024] split-K partials
    const float* __restrict__ bcat,
    const float* __restrict__ cs_r, float* __restrict__ cs_w,
    float* __restrict__ qs, float* __restrict__ pr, int step0)
{
    __shared__ __align__(16) float ql[HID];
    __shared__ __align__(16) float red[4][HID];
    __shared__ float mw[4], lw[4];

    const int g = blockIdx.x >> 2, part = blockIdx.x & 3;
    const int tid = threadIdx.x;

    // ---- LSTM cell for hidden unit `tid` (gate order i,f,g,o).
    // Redundant across the 4 parts; only part 0 writes cs/qs. cs is
    // ping-ponged across steps so parts never race on it.
    {
        float ig = bcat[tid], fg = bcat[256 + tid], gg = bcat[512 + tid], og = bcat[768 + tid];
        float cp = 0.f;
        if (!step0) {
            const float* a0 = gates_p + (size_t)g * 1024;
            const float* a1 = a0 + (size_t)512 * 1024;
            ig += a0[tid]       + a1[tid];
            fg += a0[256 + tid] + a1[256 + tid];
            gg += a0[512 + tid] + a1[512 + tid];
            og += a0[768 + tid] + a1[768 + tid];
            cp = cs_r[g * HID + tid];
        }
        float cn = sigmoidf_(fg) * cp + sigmoidf_(ig) * tanhf(gg);
        float h  = sigmoidf_(og) * tanhf(cn);
        if (part == 0) {
            cs_w[g * HID + tid] = cn;
            qs[(size_t)g * 512 + tid] = h;      // q_star[:, :256] = hs
        }
        ql[tid] = h;
    }

    const int s0 = starts[g];
    const int nn = starts[g + 1] - s0;
    if (nn <= 0) return;                        // merge_kernel writes zeros
    __syncthreads();

    const int w = tid >> 6, lane = tid & 63;
    const int j = lane >> 3;        // row within 8-row chunk
    const int s = lane & 7;         // 16B column-group within row

    const int nch = (nn + 7) >> 3;              // 8-row chunks
    const int last = s0 + nn - 1;
    const float NEG = -3.402823466e38f;

    float m_run = NEG, l_run = 0.f;
    float4 racc[8] = {};
    float4 xc[8], xn[8];

    int c = part * 4 + w;                       // chunks stride 16
    if (c < nch) {
        int node = s0 + c * 8 + j; if (node > last) node = last;
        const float* bp = x + (size_t)node * HID + s * 4;
        #pragma unroll
        for (int k = 0; k < 8; ++k) xc[k] = *(const float4*)(bp + k * 32);
    }
    for (; c < nch; c += 16) {
        if (c + 16 < nch) {
            int node = s0 + (c + 16) * 8 + j; if (node > last) node = last;
            const float* bp = x + (size_t)node * HID + s * 4;
            #pragma unroll
            for (int k = 0; k < 8; ++k) xn[k] = *(const float4*)(bp + k * 32);
        }
        const bool valid = (c * 8 + j) < nn;    // j=0 always valid for c<nch

        float e = 0.f;
        #pragma unroll
        for (int k = 0; k < 8; ++k) {
            float4 q = *(const float4*)&ql[k * 32 + s * 4];   // LDS broadcast
            e += xc[k].x * q.x + xc[k].y * q.y + xc[k].z * q.z + xc[k].w * q.w;
        }
        e += __shfl_xor(e, 1); e += __shfl_xor(e, 2); e += __shfl_xor(e, 4);
        e = valid ? e : NEG;

        float mc = fmaxf(e, __shfl_xor(e, 8));
        mc = fmaxf(mc, __shfl_xor(mc, 16));
        mc = fmaxf(mc, __shfl_xor(mc, 32));     // wave-uniform chunk max
        if (mc > m_run) {                       // wave-uniform new-max event
            float alpha = __expf(m_run - mc);   // first event: expf(-3.4e38)=0
            l_run *= alpha;
            #pragma unroll
            for (int k = 0; k < 8; ++k) {
                racc[k].x *= alpha; racc[k].y *= alpha;
                racc[k].z *= alpha; racc[k].w *= alpha;
            }
            m_run = mc;
        }
        float p = valid ? __expf(e - m_run) : 0.f;
        float ps = p;
        ps += __shfl_xor(ps, 8); ps += __shfl_xor(ps, 16); ps += __shfl_xor(ps, 32);
        l_run += ps;
        #pragma unroll
        for (int k = 0; k < 8; ++k) {
            racc[k].x += p * xc[k].x;
            racc[k].y += p * xc[k].y;
            racc[k].z += p * xc[k].z;
            racc[k].w += p * xc[k].w;
        }
        #pragma unroll
        for (int k = 0; k < 8; ++k) xc[k] = xn[k];
    }

    // fold racc across the 8 row-slots (lane bits 3..5)
    #pragma unroll
    for (int k = 0; k < 8; ++k) {
        racc[k].x += __shfl_xor(racc[k].x, 8);
        racc[k].y += __shfl_xor(racc[k].y, 8);
        racc[k].z += __shfl_xor(racc[k].z, 8);
        racc[k].w += __shfl_xor(racc[k].w, 8);
        racc[k].x += __shfl_xor(racc[k].x, 16);
        racc[k].y += __shfl_xor(racc[k].y, 16);
        racc[k].z += __shfl_xor(racc[k].z, 16);
        racc[k].w += __shfl_xor(racc[k].w, 16);
        racc[k].x += __shfl_xor(racc[k].x, 32);
        racc[k].y += __shfl_xor(racc[k].y, 32);
        racc[k].z += __shfl_xor(racc[k].z, 32);
        racc[k].w += __shfl_xor(racc[k].w, 32);
    }
    if (j == 0) {
        #pragma unroll
        for (int k = 0; k < 8; ++k) *(float4*)&red[w][k * 32 + s * 4] = racc[k];
        if (s == 0) { mw[w] = m_run; lw[w] = l_run; }
    }
    __syncthreads();

    // merge this part's 4 wave-states; write UNNORMALIZED partial (R, M, L)
    float M = fmaxf(fmaxf(mw[0], mw[1]), fmaxf(mw[2], mw[3]));
    float f0 = __expf(mw[0] - M), f1 = __expf(mw[1] - M);
    float f2 = __expf(mw[2] - M), f3 = __expf(mw[3] - M);
    float L = lw[0] * f0 + lw[1] * f1 + lw[2] * f2 + lw[3] * f3;
    float R = red[0][tid] * f0 + red[1][tid] * f1 + red[2][tid] * f2 + red[3][tid] * f3;
    float* pb = pr + (size_t)(((size_t)g << 2) + part) * 260;
    pb[tid] = R;
    if (tid == 0) { pb[256] = M; pb[257] = L; }
}

// ---------------------------------------------------------------------------
// Merge the 4 per-part partials of each graph into q_star[:, 256:512].
__global__ __launch_bounds__(256) void merge_kernel(
    const float* __restrict__ pr, const int* __restrict__ starts,
    float* __restrict__ qs)
{
    const int g = blockIdx.x, tid = threadIdx.x;
    const int nn = starts[g + 1] - starts[g];
    if (nn <= 0) { qs[(size_t)g * 512 + HID + tid] = 0.f; return; }
    const float* pb = pr + (size_t)g * 4 * 260;
    float m0 = pb[256], m1 = pb[260 + 256], m2 = pb[2 * 260 + 256], m3 = pb[3 * 260 + 256];
    float M = fmaxf(fmaxf(m0, m1), fmaxf(m2, m3));   // finite: part 0 owns chunk 0
    float f0 = __expf(m0 - M), f1 = __expf(m1 - M);
    float f2 = __expf(m2 - M), f3 = __expf(m3 - M);
    float L = pb[257] * f0 + pb[260 + 257] * f1 + pb[2 * 260 + 257] * f2 + pb[3 * 260 + 257] * f3;
    float R = pb[tid] * f0 + pb[260 + tid] * f1 + pb[2 * 260 + tid] * f2 + pb[3 * 260 + tid] * f3;
    qs[(size_t)g * 512 + HID + tid] = R / L;
}

// ---------------------------------------------------------------------------
// Cp[z][M x N] = A[M x K-slice] * B[N x K-slice]^T ; 64x64 tile, 4x4 micro,
// b128 LDS reads both operands, global prefetch. grid (N/64, M/64, S).
__global__ __launch_bounds__(256) void gemm_splitk(
    const float* __restrict__ A, int lda,
    const float* __restrict__ B, int ldb,
    float* __restrict__ Cp, int ldc, int KS, size_t slice_stride)
{
    __shared__ float As[16][76];
    __shared__ float Bs[16][76];
    const int tid = threadIdx.x;
    const int tx = tid & 15, ty = tid >> 4;
    const int m0 = blockIdx.y * 64, n0 = blockIdx.x * 64;
    const int kb = blockIdx.z * KS;
    const int r = tid >> 2, kc = (tid & 3) << 2;
    float acc[4][4] = {};

    const float* Ap = &A[(size_t)(m0 + r) * lda + kb + kc];
    const float* Bp = &B[(size_t)(n0 + r) * ldb + kb + kc];
    float4 av = *(const float4*)Ap;
    float4 bv = *(const float4*)Bp;

    for (int k0 = 0; k0 < KS; k0 += 16) {
        As[kc + 0][r] = av.x; As[kc + 1][r] = av.y; As[kc + 2][r] = av.z; As[kc + 3][r] = av.w;
        Bs[kc + 0][r] = bv.x; Bs[kc + 1][r] = bv.y; Bs[kc + 2][r] = bv.z; Bs[kc + 3][r] = bv.w;
        __syncthreads();
        if (k0 + 16 < KS) {
            av = *(const float4*)(Ap + k0 + 16);
            bv = *(const float4*)(Bp + k0 + 16);
        }
        #pragma unroll
        for (int kk = 0; kk < 16; ++kk) {
            float4 a = *(const float4*)&As[kk][ty << 2];
            float4 b = *(const float4*)&Bs[kk][tx << 2];
            acc[0][0] += a.x * b.x; acc[0][1] += a.x * b.y; acc[0][2] += a.x * b.z; acc[0][3] += a.x * b.w;
            acc[1][0] += a.y * b.x; acc[1][1] += a.y * b.y; acc[1][2] += a.y * b.z; acc[1][3] += a.y * b.w;
            acc[2][0] += a.z * b.x; acc[2][1] += a.z * b.y; acc[2][2] += a.z * b.z; acc[2][3] += a.z * b.w;
            acc[3][0] += a.w * b.x; acc[3][1] += a.w * b.y; acc[3][2] += a.w * b.z; acc[3][3] += a.w * b.w;
        }
        __syncthreads();
    }
    float* out = Cp + blockIdx.z * slice_stride;
    #pragma unroll
    for (int i = 0; i < 4; ++i) {
        float4 o = make_float4(acc[i][0], acc[i][1], acc[i][2], acc[i][3]);
        *(float4*)&out[(size_t)(m0 + ty * 4 + i) * ldc + n0 + (tx << 2)] = o;
    }
}

// ---------------------------------------------------------------------------
__global__ __launch_bounds__(256) void finalize_out(
    const float* __restrict__ op, const float* __restrict__ b_out,
    float* __restrict__ out)
{
    int i = blockIdx.x * 256 + threadIdx.x;
    if (i < 512 * 256) {
        float v = op[i] + op[131072 + i] + op[262144 + i] + op[393216 + i] + b_out[i & 255];
        out[i] = v;
    }
}

// ---------------------------------------------------------------------------
extern "C" void kernel_launch(void* const* d_in, const int* in_sizes, int n_in,
                              void* d_out, int out_size, void* d_ws, size_t ws_size,
                              hipStream_t stream)
{
    const float* x     = (const float*)d_in[0];
    const int*   batch = (const int*)d_in[1];
    const float* W_ih  = (const float*)d_in[2];
    const float* W_hh  = (const float*)d_in[3];
    const float* b_ih  = (const float*)d_in[4];
    const float* b_hh  = (const float*)d_in[5];
    const float* W_out = (const float*)d_in[6];
    const float* b_out = (const float*)d_in[7];
    float* out = (float*)d_out;
    const int n = in_sizes[1];
    (void)n_in; (void)out_size; (void)ws_size;

    char* ws = (char*)d_ws;
    float* qs      = (float*)(ws);                  // [512][512]      1 MB
    float* csA     = (float*)(ws + 0x100000);       // [512][256]      512 KB
    float* csB     = (float*)(ws + 0x180000);       // [512][256]      512 KB
    float* gates_p = (float*)(ws + 0x200000);       // [2][512][1024]  4 MB
    float* Wcat    = (float*)(ws + 0x600000);       // [1024][512]     2 MB
    float* bcat    = (float*)(ws + 0x800000);       // [1024]
    int*   starts  = (int*)  (ws + 0x801000);       // [513]
    float* pr      = (float*)(ws + 0x810000);       // [512*4][260]    2.13 MB
    float* out_p   = (float*)(ws + 0xA20000);       // [4][512][256]   2 MB (ends 0xC20000 ≈ 12.1 MiB)

    setup_kernel<<<2051, 256, 0, stream>>>(W_ih, W_hh, b_ih, b_hh, Wcat, bcat,
                                           batch, n, starts);

    for (int step = 0; step < 3; ++step) {
        if (step > 0) {
            gemm_splitk<<<dim3(16, 8, 2), 256, 0, stream>>>(
                qs, 512, Wcat, 512, gates_p, 1024, 256, (size_t)512 * 1024);
        }
        const float* cs_r = (step == 2) ? csB : csA;   // step1 reads csA
        float*       cs_w = (step == 1) ? csB : csA;   // step0->csA, step1->csB, step2->csA
        attn_kernel<<<NG * 4, 256, 0, stream>>>(
            x, starts, gates_p, bcat, cs_r, cs_w, qs, pr, step == 0);
        merge_kernel<<<NG, 256, 0, stream>>>(pr, starts, qs);
    }
    gemm_splitk<<<dim3(4, 8, 4), 256, 0, stream>>>(
        qs, 512, W_out, 512, out_p, 256, 128, (size_t)512 * 256);
    finalize_out<<<512, 256, 0, stream>>>(out_p, b_out, out);
}

// Round 8
// 418.046 us; speedup vs baseline: 1.2685x; 1.0296x over previous
//
#include <hip/hip_runtime.h>

// H=256, B=512 graphs, N=200000 nodes, 3 steps.
#define HID 256
#define NG 512

// clang native vector: __builtin_nontemporal_load requires scalar / native
// vector types (rejects HIP_vector_type<float,4>). Supports .x/.y/.z/.w.
typedef float f4 __attribute__((ext_vector_type(4)));

__device__ __forceinline__ float sigmoidf_(float v) { return 1.f / (1.f + __expf(-v)); }

// ---------------------------------------------------------------------------
// Fused setup: blocks [0,2048) build Wcat/bcat, blocks [2048,2051) binary-search
// the per-graph start offsets.
__global__ __launch_bounds__(256) void setup_kernel(
    const float* __restrict__ W_ih, const float* __restrict__ W_hh,
    const float* __restrict__ b_ih, const float* __restrict__ b_hh,
    float* __restrict__ Wcat, float* __restrict__ bcat,
    const int* __restrict__ batch, int n, int* __restrict__ starts)
{
    int b = blockIdx.x;
    if (b < 2048) {
        int idx = b * 256 + threadIdx.x;
        int k = idx & 511;
        float v = W_ih[idx];
        if (k < 256) v += W_hh[(idx >> 9) * 256 + k];
        Wcat[idx] = v;
        if (idx < 1024) bcat[idx] = b_ih[idx] + b_hh[idx];
    } else {
        int g = (b - 2048) * 256 + threadIdx.x;
        if (g > NG) return;
        if (g == NG) { starts[NG] = n; return; }
        int lo = 0, hi = n;
        while (lo < hi) {
            int mid = (lo + hi) >> 1;
            if (batch[mid] < g) lo = mid + 1; else hi = mid;
        }
        starts[g] = lo;
    }
}

// ---------------------------------------------------------------------------
// Fused LSTM cell + attention + readout. One block per graph, 4 waves.
// Wave w owns 8-row chunks c ≡ w (mod 4). Depth-2 software pipeline with a
// 3-buffer (P/Q/R) round-robin. x loads are NONTEMPORAL (nt bit): the x
// stream is a 205MB read-allocating churn through the 256MB L3 with zero
// reuse before eviction — nt bypasses the allocate path, the suspected
// chip-level ~2 TB/s cap (depth/occupancy/compute levers all measured null).
// Online-softmax state entirely in registers; 4 wave-states merged at end.

#define LOADB(BUF, CIDX) do {                                               \
    int node_ = s0 + (CIDX) * 8 + j; if (node_ > last) node_ = last;        \
    const float* bp_ = x + (size_t)node_ * HID + s * 4;                     \
    _Pragma("unroll")                                                       \
    for (int k = 0; k < 8; ++k)                                             \
        BUF[k] = __builtin_nontemporal_load((const f4*)(bp_ + k * 32));     \
} while (0)

#define COMPUTE(BUF, CIDX) do {                                             \
    const bool valid_ = ((CIDX) * 8 + j) < nn;                              \
    float e_ = 0.f;                                                         \
    _Pragma("unroll")                                                       \
    for (int k = 0; k < 8; ++k)                                             \
        e_ += BUF[k].x * qf[k].x + BUF[k].y * qf[k].y                       \
            + BUF[k].z * qf[k].z + BUF[k].w * qf[k].w;                      \
    e_ += __shfl_xor(e_, 1); e_ += __shfl_xor(e_, 2); e_ += __shfl_xor(e_, 4); \
    e_ = valid_ ? e_ : NEG;                                                 \
    float mc_ = e_;                                                         \
    mc_ = fmaxf(mc_, __shfl_xor(mc_, 8));                                   \
    mc_ = fmaxf(mc_, __shfl_xor(mc_, 16));                                  \
    mc_ = fmaxf(mc_, __shfl_xor(mc_, 32));                                  \
    float mnew_ = fmaxf(m_run, mc_);                                        \
    float alpha_ = __expf(m_run - mnew_);                                   \
    float p_ = valid_ ? __expf(e_ - mnew_) : 0.f;                           \
    float ps_ = p_;                                                         \
    ps_ += __shfl_xor(ps_, 8); ps_ += __shfl_xor(ps_, 16); ps_ += __shfl_xor(ps_, 32); \
    l_run = l_run * alpha_ + ps_;                                           \
    m_run = mnew_;                                                          \
    _Pragma("unroll")                                                       \
    for (int k = 0; k < 8; ++k) {                                           \
        racc[k].x = racc[k].x * alpha_ + p_ * BUF[k].x;                     \
        racc[k].y = racc[k].y * alpha_ + p_ * BUF[k].y;                     \
        racc[k].z = racc[k].z * alpha_ + p_ * BUF[k].z;                     \
        racc[k].w = racc[k].w * alpha_ + p_ * BUF[k].w;                     \
    }                                                                       \
} while (0)

__global__ __launch_bounds__(256) void attn_kernel(
    const float* __restrict__ x, const int* __restrict__ starts,
    const float* __restrict__ gates_p,      // [2][512][1024] split-K partials
    const float* __restrict__ bcat, float* __restrict__ cs,
    float* __restrict__ qs, int step0)
{
    __shared__ __align__(16) float ql[HID];
    __shared__ __align__(16) float red[4][HID];
    __shared__ float mw[4], lw[4];

    const int g = blockIdx.x;
    const int tid = threadIdx.x;

    // ---- LSTM cell for hidden unit `tid` (gate order i,f,g,o)
    {
        float ig = bcat[tid], fg = bcat[256 + tid], gg = bcat[512 + tid], og = bcat[768 + tid];
        float cp = 0.f;
        if (!step0) {
            const float* a0 = gates_p + (size_t)g * 1024;
            const float* a1 = a0 + (size_t)512 * 1024;
            ig += a0[tid]       + a1[tid];
            fg += a0[256 + tid] + a1[256 + tid];
            gg += a0[512 + tid] + a1[512 + tid];
            og += a0[768 + tid] + a1[768 + tid];
            cp = cs[g * HID + tid];
        }
        float cn = sigmoidf_(fg) * cp + sigmoidf_(ig) * tanhf(gg);
        float h  = sigmoidf_(og) * tanhf(cn);
        cs[g * HID + tid] = cn;
        qs[(size_t)g * 512 + tid] = h;      // q_star[:, :256] = hs
        ql[tid] = h;
    }

    const int s0 = starts[g];
    const int nn = starts[g + 1] - s0;
    if (nn <= 0) { qs[(size_t)g * 512 + HID + tid] = 0.f; return; }
    __syncthreads();

    const int w = tid >> 6, lane = tid & 63;
    const int j = lane >> 3;        // row within 8-row chunk
    const int s = lane & 7;         // 16B column-group within row

    f4 qf[8];
    #pragma unroll
    for (int k = 0; k < 8; ++k) qf[k] = *(const f4*)&ql[k * 32 + s * 4];

    const int nch = (nn + 7) >> 3;          // 8-row chunks
    const int last = s0 + nn - 1;
    const float NEG = -3.402823466e38f;

    float m_run = NEG, l_run = 0.f;
    f4 racc[8] = {};
    f4 P[8], Q[8], R[8];

    // wave's chunks: w, w+4, w+8, ... ; pipeline depth 2 (P,Q in flight ahead)
    int c = w;
    if (c < nch)     LOADB(P, c);
    if (c + 4 < nch) LOADB(Q, c + 4);
    for (; c < nch; c += 12) {
        if (c + 8 < nch)  LOADB(R, c + 8);
        COMPUTE(P, c);
        if (c + 4 >= nch) break;
        if (c + 12 < nch) LOADB(P, c + 12);
        COMPUTE(Q, c + 4);
        if (c + 8 >= nch) break;
        if (c + 16 < nch) LOADB(Q, c + 16);
        COMPUTE(R, c + 8);
    }

    // fold racc across the 8 row-slots (lane bits 3..5); once per pass
    #pragma unroll
    for (int k = 0; k < 8; ++k) {
        racc[k].x += __shfl_xor(racc[k].x, 8);
        racc[k].y += __shfl_xor(racc[k].y, 8);
        racc[k].z += __shfl_xor(racc[k].z, 8);
        racc[k].w += __shfl_xor(racc[k].w, 8);
        racc[k].x += __shfl_xor(racc[k].x, 16);
        racc[k].y += __shfl_xor(racc[k].y, 16);
        racc[k].z += __shfl_xor(racc[k].z, 16);
        racc[k].w += __shfl_xor(racc[k].w, 16);
        racc[k].x += __shfl_xor(racc[k].x, 32);
        racc[k].y += __shfl_xor(racc[k].y, 32);
        racc[k].z += __shfl_xor(racc[k].z, 32);
        racc[k].w += __shfl_xor(racc[k].w, 32);
    }
    if (j == 0) {
        #pragma unroll
        for (int k = 0; k < 8; ++k) *(f4*)&red[w][k * 32 + s * 4] = racc[k];
        if (s == 0) { mw[w] = m_run; lw[w] = l_run; }
    }
    __syncthreads();

    // merge the 4 wave-states (empty wave: m=NEG -> factor exp(NEG-M)=0)
    float M = fmaxf(fmaxf(mw[0], mw[1]), fmaxf(mw[2], mw[3]));
    float f0 = __expf(mw[0] - M), f1 = __expf(mw[1] - M);
    float f2 = __expf(mw[2] - M), f3 = __expf(mw[3] - M);
    float L = lw[0] * f0 + lw[1] * f1 + lw[2] * f2 + lw[3] * f3;
    float r = red[0][tid] * f0 + red[1][tid] * f1 + red[2][tid] * f2 + red[3][tid] * f3;
    qs[(size_t)g * 512 + HID + tid] = r / L;     // q_star[:, 256:512] = r
}

// ---------------------------------------------------------------------------
// Cp[z][M x N] = A[M x K-slice] * B[N x K-slice]^T ; 64x64 tile, 4x4 micro,
// b128 LDS reads both operands, global prefetch. grid (N/64, M/64, S).
__global__ __launch_bounds__(256) void gemm_splitk(
    const float* __restrict__ A, int lda,
    const float* __restrict__ B, int ldb,
    float* __restrict__ Cp, int ldc, int KS, size_t slice_stride)
{
    __shared__ float As[16][76];
    __shared__ float Bs[16][76];
    const int tid = threadIdx.x;
    const int tx = tid & 15, ty = tid >> 4;
    const int m0 = blockIdx.y * 64, n0 = blockIdx.x * 64;
    const int kb = blockIdx.z * KS;
    const int r = tid >> 2, kc = (tid & 3) << 2;
    float acc[4][4] = {};

    const float* Ap = &A[(size_t)(m0 + r) * lda + kb + kc];
    const float* Bp = &B[(size_t)(n0 + r) * ldb + kb + kc];
    float4 av = *(const float4*)Ap;
    float4 bv = *(const float4*)Bp;

    for (int k0 = 0; k0 < KS; k0 += 16) {
        As[kc + 0][r] = av.x; As[kc + 1][r] = av.y; As[kc + 2][r] = av.z; As[kc + 3][r] = av.w;
        Bs[kc + 0][r] = bv.x; Bs[kc + 1][r] = bv.y; Bs[kc + 2][r] = bv.z; Bs[kc + 3][r] = bv.w;
        __syncthreads();
        if (k0 + 16 < KS) {
            av = *(const float4*)(Ap + k0 + 16);
            bv = *(const float4*)(Bp + k0 + 16);
        }
        #pragma unroll
        for (int kk = 0; kk < 16; ++kk) {
            float4 a = *(const float4*)&As[kk][ty << 2];
            float4 b = *(const float4*)&Bs[kk][tx << 2];
            acc[0][0] += a.x * b.x; acc[0][1] += a.x * b.y; acc[0][2] += a.x * b.z; acc[0][3] += a.x * b.w;
            acc[1][0] += a.y * b.x; acc[1][1] += a.y * b.y; acc[1][2] += a.y * b.z; acc[1][3] += a.y * b.w;
            acc[2][0] += a.z * b.x; acc[2][1] += a.z * b.y; acc[2][2] += a.z * b.z; acc[2][3] += a.z * b.w;
            acc[3][0] += a.w * b.x; acc[3][1] += a.w * b.y; acc[3][2] += a.w * b.z; acc[3][3] += a.w * b.w;
        }
        __syncthreads();
    }
    float* out = Cp + blockIdx.z * slice_stride;
    #pragma unroll
    for (int i = 0; i < 4; ++i) {
        float4 o = make_float4(acc[i][0], acc[i][1], acc[i][2], acc[i][3]);
        *(float4*)&out[(size_t)(m0 + ty * 4 + i) * ldc + n0 + (tx << 2)] = o;
    }
}

// ---------------------------------------------------------------------------
__global__ __launch_bounds__(256) void finalize_out(
    const float* __restrict__ op, const float* __restrict__ b_out,
    float* __restrict__ out)
{
    int i = blockIdx.x * 256 + threadIdx.x;
    if (i < 512 * 256) {
        float v = op[i] + op[131072 + i] + op[262144 + i] + op[393216 + i] + b_out[i & 255];
        out[i] = v;
    }
}

// ---------------------------------------------------------------------------
extern "C" void kernel_launch(void* const* d_in, const int* in_sizes, int n_in,
                              void* d_out, int out_size, void* d_ws, size_t ws_size,
                              hipStream_t stream)
{
    const float* x     = (const float*)d_in[0];
    const int*   batch = (const int*)d_in[1];
    const float* W_ih  = (const float*)d_in[2];
    const float* W_hh  = (const float*)d_in[3];
    const float* b_ih  = (const float*)d_in[4];
    const float* b_hh  = (const float*)d_in[5];
    const float* W_out = (const float*)d_in[6];
    const float* b_out = (const float*)d_in[7];
    float* out = (float*)d_out;
    const int n = in_sizes[1];
    (void)n_in; (void)out_size; (void)ws_size;

    char* ws = (char*)d_ws;
    float* qs      = (float*)(ws);                  // [512][512]      1 MB
    float* cs      = (float*)(ws + 0x100000);       // [512][256]      512 KB
    float* gates_p = (float*)(ws + 0x180000);       // [2][512][1024]  4 MB
    float* Wcat    = (float*)(ws + 0x580000);       // [1024][512]     2 MB
    float* bcat    = (float*)(ws + 0x780000);       // [1024]
    int*   starts  = (int*)  (ws + 0x781000);       // [513]
    float* out_p   = (float*)(ws + 0x790000);       // [4][512][256]   2 MB

    setup_kernel<<<2051, 256, 0, stream>>>(W_ih, W_hh, b_ih, b_hh, Wcat, bcat,
                                           batch, n, starts);

    for (int step = 0; step < 3; ++step) {
        if (step > 0) {
            gemm_splitk<<<dim3(16, 8, 2), 256, 0, stream>>>(
                qs, 512, Wcat, 512, gates_p, 1024, 256, (size_t)512 * 1024);
        }
        attn_kernel<<<NG, 256, 0, stream>>>(
            x, starts, gates_p, bcat, cs, qs, step == 0);
    }
    gemm_splitk<<<dim3(4, 8, 4), 256, 0, stream>>>(
        qs, 512, W_out, 512, out_p, 256, 128, (size_t)512 * 256);
    finalize_out<<<512, 256, 0, stream>>>(out_p, b_out, out);
}